// Round 8
// baseline (287.680 us; speedup 1.0000x reference)
//
#include <hip/hip_runtime.h>
#include <stdint.h>

#define H_ 4
#define N_ 512
#define D_ 64
#define E_ (N_ * N_)        // 262144 edges per head
#define HE_ (H_ * E_)       // 1048576
#define EPS_ 1e-10f
#define NWG_ 1024ull

// Partitionable threefry (verified rounds 1-3): counter (hi=0, lo=j), out = x0^x1.
__device__ __forceinline__ void tf2x32(unsigned x0, unsigned x1,
                                       unsigned& o0, unsigned& o1) {
  const unsigned ks0 = 0u;          // key hi of seed 42
  const unsigned ks1 = 42u;         // key lo
  const unsigned ks2 = 0x1BD11BDAu ^ ks0 ^ ks1;
  x0 += ks0; x1 += ks1;
#define TFR(r) { x0 += x1; x1 = (x1 << (r)) | (x1 >> (32 - (r))); x1 ^= x0; }
  TFR(13) TFR(15) TFR(26) TFR(6)
  x0 += ks1; x1 += ks2 + 1u;
  TFR(17) TFR(29) TFR(16) TFR(24)
  x0 += ks2; x1 += ks0 + 2u;
  TFR(13) TFR(15) TFR(26) TFR(6)
  x0 += ks0; x1 += ks1 + 3u;
  TFR(17) TFR(29) TFR(16) TFR(24)
  x0 += ks1; x1 += ks2 + 4u;
  TFR(13) TFR(15) TFR(26) TFR(6)
  x0 += ks2; x1 += ks0 + 5u;
#undef TFR
  o0 = x0; o1 = x1;
}

__device__ __forceinline__ unsigned rng_bits(unsigned j) {
  unsigned a, b;
  tf2x32(0u, j, a, b);
  return a ^ b;
}

__device__ __forceinline__ float u01(unsigned bits) {
  return __uint_as_float((bits >> 9) | 0x3f800000u) - 1.0f;
}

// Grid barrier, race-free by construction: bar[16] (128B-spread counters) is
// hipMemsetAsync'd to 0 before launch, so the target is absolute (no entry
// capture). Signal: 1 device-scope atomicAdd per block into counter (bl&15)
// -> 64 adds/counter, parallel across L2 banks. Poll: agent-scope atomic
// loads (no exclusive ownership -> many concurrent pollers scale) + s_sleep
// backoff. Spin is iteration-bounded: a broken barrier fails absmax, never
// hangs the container. Primitive set (threadfence + device atomics + plain
// stores/loads) is the one verified cross-block by topk_fused on this chip.
#define GBAR(PH)                                                          \
  do {                                                                    \
    __syncthreads();                                                      \
    if (t == 0) {                                                         \
      __threadfence();                                                    \
      atomicAdd(&bar[(bl & 15) << 4], 1ull);                              \
      const unsigned long long _tgt = (unsigned long long)(PH)*NWG_;      \
      for (long _i = 0; _i < 2000000L; ++_i) {                            \
        unsigned long long _s = 0ull;                                     \
        _Pragma("unroll")                                                 \
        for (int _k = 0; _k < 16; ++_k)                                   \
          _s += __hip_atomic_load(&bar[_k << 4], __ATOMIC_RELAXED,        \
                                  __HIP_MEMORY_SCOPE_AGENT);              \
        if (_s >= _tgt) break;                                            \
        __builtin_amdgcn_s_sleep(4);                                      \
      }                                                                   \
      __threadfence();                                                    \
    }                                                                     \
    __syncthreads();                                                      \
  } while (0)

// ---------------- single cooperative kernel: 1024 blocks x 256 threads
// = 256 CU x 4 blocks/CU under launch_bounds(256,4) (LDS 22.3KB -> 7/CU,
// VGPR cap 128 -> 4/CU; same shape as the verified round-4 edge kernel).
// ALL FP chains bit-identical to the verified multi-kernel version.
__global__ __launch_bounds__(256, 4) void mega_kernel(
    const float* __restrict__ feats, const float* __restrict__ W_out,
    const float* __restrict__ b_out, const float* __restrict__ W_cat,
    const float* __restrict__ b_cat, float* __restrict__ out,
    float* __restrict__ A, float* __restrict__ B,
    unsigned long long* __restrict__ blockmax,
    unsigned long long* __restrict__ cand, unsigned* __restrict__ cnt,
    unsigned long long* __restrict__ bar) {
  __shared__ __align__(16) float Ash[64][68];
  __shared__ __align__(16) float Bsh[16][64];
  __shared__ float4 bsh4[16];
  __shared__ float4 wc4[32];
  __shared__ float bc2[2];
  __shared__ unsigned long long wmax[4];
  __shared__ unsigned long long thrS;

  const int t = threadIdx.x;
  const int bl = blockIdx.x;                 // 0..1023
  const int bx = bl & 7, by = (bl >> 3) & 31, h = bl >> 8;
  const int snd_base = bx * 64;
  const int rec_base = by * 16;

  // ======== phase 0: A/B projection (2 rows/block) + sparse-zero + cnt ====
  if (bl == 0 && t < 4) cnt[t] = 0u;         // ws poisoned each call
  {
    // zero this block's contiguous 1024-edge sparse chunk (winners in ph3)
    ((float4*)(out + 2 * HE_ + ((unsigned)h << 18) + (unsigned)(bl & 255) * 1024u))[t] =
        make_float4(0.f, 0.f, 0.f, 0.f);

    const int g = t >> 6;                    // 4 groups of 64 lanes
    const int d = t & 63;
    const int row = bl * 2 + (g & 1);        // groups 0,1 active: rows 0..2047
    float* fsh = &Ash[0][0];                 // 128-float LDS scratch
    if (g < 2) fsh[(g << 6) + d] = feats[row * D_ + d];
    __syncthreads();
    if (g < 2) {
      const float* fr = &fsh[g << 6];
      float a = 0.f, b = 0.f;
#pragma unroll 8
      for (int k = 0; k < D_; ++k) {
        float fv = fr[k];
        a = fmaf(fv, W_out[k * D_ + d], a);          // sender rows [0,64)
        b = fmaf(fv, W_out[(k + D_) * D_ + d], b);   // receiver rows [64,128)
      }
      A[row * D_ + d] = a;
      B[row * D_ + d] = b;
    }
  }
  GBAR(1);

  // ======== phase 1: edge tile (verbatim round-4 edge_kernel body) ========
  {
    const float4* A4 = (const float4*)(A + (h * N_ + snd_base) * D_);
    for (int i = t; i < 1024; i += 256)
      *(float4*)&Ash[i >> 4][(i & 15) << 2] = A4[i];
    const float4* B4 = (const float4*)(B + (h * N_ + rec_base) * D_);
    *(float4*)&Bsh[t >> 4][(t & 15) << 2] = B4[t];
  }
  if (t < 16) bsh4[t] = ((const float4*)b_out)[t];
  else if (t < 48) wc4[t - 16] = ((const float4*)W_cat)[t - 16];
  else if (t == 48) { bc2[0] = b_cat[0]; bc2[1] = b_cat[1]; }
  __syncthreads();

  const int s = t & 63;
  const int rg = (t >> 6) * 4;

  float l0[4], l1[4];
#pragma unroll
  for (int r = 0; r < 4; ++r) { l0[r] = 0.f; l1[r] = 0.f; }

#pragma unroll
  for (int d4 = 0; d4 < 16; ++d4) {
    const float4 a0 = *(const float4*)&Ash[s][d4 << 2];
    const float4 bd = bsh4[d4];
    const float4 wA = wc4[2 * d4];
    const float4 wB = wc4[2 * d4 + 1];
#pragma unroll
    for (int r = 0; r < 4; ++r) {
      const float4 bv = *(const float4*)&Bsh[rg + r][d4 << 2];
      float t0;
      t0 = fmaxf((a0.x + bv.x) + bd.x, 0.f);
      l0[r] = fmaf(t0, wA.x, l0[r]); l1[r] = fmaf(t0, wA.y, l1[r]);
      t0 = fmaxf((a0.y + bv.y) + bd.y, 0.f);
      l0[r] = fmaf(t0, wA.z, l0[r]); l1[r] = fmaf(t0, wA.w, l1[r]);
      t0 = fmaxf((a0.z + bv.z) + bd.z, 0.f);
      l0[r] = fmaf(t0, wB.x, l0[r]); l1[r] = fmaf(t0, wB.y, l1[r]);
      t0 = fmaxf((a0.w + bv.w) + bd.w, 0.f);
      l0[r] = fmaf(t0, wB.z, l0[r]); l1[r] = fmaf(t0, wB.w, l1[r]);
    }
  }

  unsigned long long mk = 0ull;
#pragma unroll
  for (int r = 0; r < 4; ++r) {
    float L0 = l0[r] + bc2[0];
    float L1 = l1[r] + bc2[1];
    const unsigned snd = (unsigned)(snd_base + s);
    const unsigned rec = (unsigned)(rec_base + rg + r);
    const unsigned e = rec * (unsigned)N_ + snd;
    const unsigned base = ((unsigned)h << 18) + e;
    const unsigned j0 = base * 2u;

    float uu0 = u01(rng_bits(j0));
    float uu1 = u01(rng_bits(j0 + 1u));
    float g0 = -logf(-logf(uu0 + EPS_) + EPS_);
    float g1 = -logf(-logf(uu1 + EPS_) + EPS_);

    float cm = ((L1 + g1) > (L0 + g0)) ? 1.0f : 0.0f;

    float lm = fmaxf(L0, L1);
    float p0 = expf(L0 - lm), p1 = expf(L1 - lm);
    float pr = p1 / (p0 + p1);

    out[base] = cm;
    out[HE_ + base] = pr;

    unsigned long long key =
        ((unsigned long long)__float_as_uint(pr) << 32) | (unsigned)(~e);
    mk = key > mk ? key : mk;
  }

#pragma unroll
  for (int off = 32; off; off >>= 1) {
    unsigned long long o = __shfl_xor(mk, off, 64);
    mk = o > mk ? o : mk;
  }
  if ((t & 63) == 0) wmax[t >> 6] = mk;
  __syncthreads();
  if (t == 0) {
    unsigned long long m = wmax[0];
#pragma unroll
    for (int i = 1; i < 4; ++i) m = wmax[i] > m ? wmax[i] : m;
    blockmax[h * 256 + (bl & 255)] = m;      // 256 tile-chunks/head
  }
  GBAR(2);

  // ======== phase 2: per-head threshold + candidate compaction ========
  // thr = 64th-largest of the 256 tile maxes. >=64 distinct elements (the 64
  // chunk-max edges) have key >= thr, so true 64th-largest key >= thr: all
  // top-64 survive regardless of scan partition.
  {
    unsigned long long* keyS = (unsigned long long*)&Ash[0][0];  // 2 KB
    keyS[t] = blockmax[h * 256 + t];
    __syncthreads();
    {
      unsigned long long my = keyS[t];
      int rank = 0;
      for (int j = 0; j < 256; ++j) rank += (keyS[j] > my);
      if (rank == 63) thrS = my;   // exact (keys unique)
    }
    __syncthreads();
    const unsigned long long thr = thrS;

    const unsigned e0 = (unsigned)(bl & 255) * 1024u + (unsigned)t * 4u;
    float4 p = *(const float4*)(out + HE_ + ((unsigned)h << 18) + e0);
    float pv[4] = {p.x, p.y, p.z, p.w};
#pragma unroll
    for (int k2 = 0; k2 < 4; ++k2) {
      unsigned e = e0 + (unsigned)k2;
      unsigned long long key =
          ((unsigned long long)__float_as_uint(pv[k2]) << 32) | (unsigned)(~e);
      if (key >= thr) {
        unsigned pos = atomicAdd(&cnt[h], 1u);   // ~155 expected << 512
        if (pos < 512u) cand[h * 512 + pos] = key;
      }
    }
  }
  GBAR(3);

  // ======== phase 3: blocks 0-3 select top-64 per head, scatter ones ====
  if (bl < 4) {
    const int h3 = bl;
    unsigned n = atomicAdd(&cnt[h3], 0u);
    if (n > 512u) n = 512u;
    unsigned long long* k512 = (unsigned long long*)&Ash[0][0];  // 4 KB
    unsigned long long m0 = (t < (int)n) ? cand[h3 * 512 + t] : 0ull;
    unsigned long long m1 = (t + 256 < (int)n) ? cand[h3 * 512 + t + 256] : 0ull;
    k512[t] = m0;
    k512[t + 256] = m1;
    __syncthreads();
    int r0 = 0, r1 = 0;
#pragma unroll 8
    for (int j = 0; j < 512; ++j) {
      unsigned long long kj = k512[j];
      r0 += (kj > m0);
      r1 += (kj > m1);
    }
    if (m0 != 0ull && r0 < 64) {
      unsigned e = ~(unsigned)(m0 & 0xFFFFFFFFull);
      if (e < (unsigned)E_) out[2 * HE_ + ((unsigned)h3 << 18) + e] = 1.0f;
    }
    if (m1 != 0ull && r1 < 64) {
      unsigned e = ~(unsigned)(m1 & 0xFFFFFFFFull);
      if (e < (unsigned)E_) out[2 * HE_ + ((unsigned)h3 << 18) + e] = 1.0f;
    }
  }
}

// ================= FALLBACK: verified round-4 three-kernel path =============
__global__ __launch_bounds__(256) void precompute_ab(
    const float* __restrict__ feats, const float* __restrict__ W_out,
    float* __restrict__ A, float* __restrict__ B,
    unsigned* __restrict__ cnt, unsigned* __restrict__ done) {
  int row = blockIdx.x * 4 + (threadIdx.x >> 6);
  int d = threadIdx.x & 63;
  if (blockIdx.x == 0) {
    if (threadIdx.x < 4) cnt[threadIdx.x] = 0u;
    else if (threadIdx.x < 8) done[threadIdx.x - 4] = 0u;
  }
  __shared__ float f[4][64];
  f[threadIdx.x >> 6][d] = feats[row * D_ + d];
  __syncthreads();
  const float* fr = f[threadIdx.x >> 6];
  float a = 0.f, b = 0.f;
#pragma unroll 8
  for (int k = 0; k < D_; ++k) {
    float fv = fr[k];
    a = fmaf(fv, W_out[k * D_ + d], a);
    b = fmaf(fv, W_out[(k + D_) * D_ + d], b);
  }
  A[row * D_ + d] = a;
  B[row * D_ + d] = b;
}

__global__ __launch_bounds__(256, 4) void edge_kernel(
    const float* __restrict__ A, const float* __restrict__ B,
    const float* __restrict__ b_out, const float* __restrict__ W_cat,
    const float* __restrict__ b_cat, float* __restrict__ out,
    unsigned long long* __restrict__ blockmax) {
  __shared__ __align__(16) float Ash[64][68];
  __shared__ __align__(16) float Bsh[16][64];
  __shared__ float4 bsh4[16];
  __shared__ float4 wc4[32];
  __shared__ float bc2[2];
  __shared__ unsigned long long wmax[4];

  const int t = threadIdx.x;
  const int h = blockIdx.z;
  const int snd_base = blockIdx.x * 64;
  const int rec_base = blockIdx.y * 16;

  {
    const float4* A4 = (const float4*)(A + (h * N_ + snd_base) * D_);
    for (int i = t; i < 1024; i += 256)
      *(float4*)&Ash[i >> 4][(i & 15) << 2] = A4[i];
    const float4* B4 = (const float4*)(B + (h * N_ + rec_base) * D_);
    *(float4*)&Bsh[t >> 4][(t & 15) << 2] = B4[t];
  }
  if (t < 16) bsh4[t] = ((const float4*)b_out)[t];
  else if (t < 48) wc4[t - 16] = ((const float4*)W_cat)[t - 16];
  else if (t == 48) { bc2[0] = b_cat[0]; bc2[1] = b_cat[1]; }
  __syncthreads();

  const int s = t & 63;
  const int rg = (t >> 6) * 4;

  float l0[4], l1[4];
#pragma unroll
  for (int r = 0; r < 4; ++r) { l0[r] = 0.f; l1[r] = 0.f; }

#pragma unroll
  for (int d4 = 0; d4 < 16; ++d4) {
    const float4 a0 = *(const float4*)&Ash[s][d4 << 2];
    const float4 bd = bsh4[d4];
    const float4 wA = wc4[2 * d4];
    const float4 wB = wc4[2 * d4 + 1];
#pragma unroll
    for (int r = 0; r < 4; ++r) {
      const float4 bv = *(const float4*)&Bsh[rg + r][d4 << 2];
      float t0;
      t0 = fmaxf((a0.x + bv.x) + bd.x, 0.f);
      l0[r] = fmaf(t0, wA.x, l0[r]); l1[r] = fmaf(t0, wA.y, l1[r]);
      t0 = fmaxf((a0.y + bv.y) + bd.y, 0.f);
      l0[r] = fmaf(t0, wA.z, l0[r]); l1[r] = fmaf(t0, wA.w, l1[r]);
      t0 = fmaxf((a0.z + bv.z) + bd.z, 0.f);
      l0[r] = fmaf(t0, wB.x, l0[r]); l1[r] = fmaf(t0, wB.y, l1[r]);
      t0 = fmaxf((a0.w + bv.w) + bd.w, 0.f);
      l0[r] = fmaf(t0, wB.z, l0[r]); l1[r] = fmaf(t0, wB.w, l1[r]);
    }
  }

  unsigned long long mk = 0ull;
#pragma unroll
  for (int r = 0; r < 4; ++r) {
    float L0 = l0[r] + bc2[0];
    float L1 = l1[r] + bc2[1];
    const unsigned snd = (unsigned)(snd_base + s);
    const unsigned rec = (unsigned)(rec_base + rg + r);
    const unsigned e = rec * (unsigned)N_ + snd;
    const unsigned base = ((unsigned)h << 18) + e;
    const unsigned j0 = base * 2u;

    float uu0 = u01(rng_bits(j0));
    float uu1 = u01(rng_bits(j0 + 1u));
    float g0 = -logf(-logf(uu0 + EPS_) + EPS_);
    float g1 = -logf(-logf(uu1 + EPS_) + EPS_);

    float cm = ((L1 + g1) > (L0 + g0)) ? 1.0f : 0.0f;

    float lm = fmaxf(L0, L1);
    float p0 = expf(L0 - lm), p1 = expf(L1 - lm);
    float pr = p1 / (p0 + p1);

    out[base] = cm;
    out[HE_ + base] = pr;

    unsigned long long key =
        ((unsigned long long)__float_as_uint(pr) << 32) | (unsigned)(~e);
    mk = key > mk ? key : mk;
  }

#pragma unroll
  for (int off = 32; off; off >>= 1) {
    unsigned long long o = __shfl_xor(mk, off, 64);
    mk = o > mk ? o : mk;
  }
  if ((t & 63) == 0) wmax[t >> 6] = mk;
  __syncthreads();
  if (t == 0) {
    unsigned long long m = wmax[0];
#pragma unroll
    for (int i = 1; i < 4; ++i) m = wmax[i] > m ? wmax[i] : m;
    blockmax[h * 256 + blockIdx.y * gridDim.x + blockIdx.x] = m;
  }
}

__global__ __launch_bounds__(512) void topk_fused(
    const float* __restrict__ prob, const unsigned long long* __restrict__ blockmax,
    unsigned* __restrict__ cnt, unsigned* __restrict__ done,
    unsigned long long* __restrict__ cand, float* __restrict__ sparse) {
  __shared__ unsigned long long keys[512];
  __shared__ unsigned long long thrS;
  __shared__ unsigned tkS;
  const int t = threadIdx.x, h = blockIdx.y, blk = blockIdx.x;

  if (t < 256) keys[t] = blockmax[h * 256 + t];
  __syncthreads();
  if (t < 256) {
    unsigned long long my = keys[t];
    int rank = 0;
    for (int j = 0; j < 256; ++j) rank += (keys[j] > my);
    if (rank == 63) thrS = my;
  }
  __syncthreads();
  const unsigned long long thr = thrS;

  const unsigned seg = (unsigned)blk * 4096u;
  {
    float4* sp4 = (float4*)(sparse + (unsigned)h * E_ + seg);
    const float4 z = make_float4(0.f, 0.f, 0.f, 0.f);
#pragma unroll
    for (int i = 0; i < 2; ++i) sp4[t + i * 512] = z;
  }
#pragma unroll
  for (int i = 0; i < 2; ++i) {
    const unsigned e0 = seg + (unsigned)i * 2048u + (unsigned)t * 4u;
    float4 p = *(const float4*)(prob + (unsigned)h * E_ + e0);
    float pv[4] = {p.x, p.y, p.z, p.w};
#pragma unroll
    for (int k2 = 0; k2 < 4; ++k2) {
      unsigned e = e0 + (unsigned)k2;
      unsigned long long key =
          ((unsigned long long)__float_as_uint(pv[k2]) << 32) | (unsigned)(~e);
      if (key >= thr) {
        unsigned pos = atomicAdd(&cnt[h], 1u);
        if (pos < 512u) cand[h * 512 + pos] = key;
      }
    }
  }
  __syncthreads();
  if (t == 0) { __threadfence(); tkS = atomicAdd(&done[h], 1u); }
  __syncthreads();

  if (tkS == 63u) {
    if (t == 0) __threadfence();
    __syncthreads();
    unsigned n = atomicAdd(&cnt[h], 0u);
    if (n > 512u) n = 512u;
    unsigned long long my = (t < (int)n) ? cand[h * 512 + t] : 0ull;
    keys[t] = my;
    __syncthreads();
    int rank = 0;
#pragma unroll 8
    for (int j = 0; j < 512; ++j) rank += (keys[j] > my);
    if (my != 0ull && rank < 64) {
      unsigned e = ~(unsigned)(my & 0xFFFFFFFFull);
      if (e < (unsigned)E_) sparse[(unsigned)h * E_ + e] = 1.0f;
    }
  }
}

extern "C" void kernel_launch(void* const* d_in, const int* in_sizes, int n_in,
                              void* d_out, int out_size, void* d_ws, size_t ws_size,
                              hipStream_t stream) {
  const float* feats = (const float*)d_in[0];
  const float* W_out = (const float*)d_in[1];
  const float* b_out = (const float*)d_in[2];
  const float* W_cat = (const float*)d_in[3];
  const float* b_cat = (const float*)d_in[4];
  float* out = (float*)d_out;

  // workspace: A | B | blockmax | cand | cnt(4) | done(4) ... bar @ 4MB
  float* A = (float*)d_ws;
  float* B = A + H_ * N_ * D_;
  unsigned long long* blockmax = (unsigned long long*)(B + H_ * N_ * D_);
  unsigned long long* cand = blockmax + H_ * 256;
  unsigned* cnt = (unsigned*)(cand + H_ * 512);
  unsigned* done = cnt + H_;
  unsigned long long* bar = (unsigned long long*)((char*)d_ws + (4u << 20));

  // zero the 16 spread barrier counters (16 x 128B = 2048B). memset-on-stream
  // is harness-legal (its own reset uses hipMemsetAsync) and replays per graph
  // iteration, so bar==0 at every call: barrier targets are absolute.
  hipMemsetAsync((void*)bar, 0, 16 * 16 * sizeof(unsigned long long), stream);

  void* args[] = {(void*)&feats, (void*)&W_out, (void*)&b_out, (void*)&W_cat,
                  (void*)&b_cat, (void*)&out,   (void*)&A,     (void*)&B,
                  (void*)&blockmax, (void*)&cand, (void*)&cnt, (void*)&bar};
  hipError_t err = hipLaunchCooperativeKernel(
      reinterpret_cast<void*>(mega_kernel), dim3(1024), dim3(256), args, 0,
      stream);
  if (err != hipSuccess) {
    // verified round-4 path (112.06 us)
    precompute_ab<<<dim3(H_ * N_ / 4), dim3(256), 0, stream>>>(feats, W_out, A,
                                                               B, cnt, done);
    edge_kernel<<<dim3(N_ / 64, N_ / 16, H_), dim3(256), 0, stream>>>(
        A, B, b_out, W_cat, b_cat, out, blockmax);
    topk_fused<<<dim3(64, H_), dim3(512), 0, stream>>>(out + HE_, blockmax,
                                                       cnt, done, cand,
                                                       out + 2 * HE_);
  }
}

// Round 9
// 252.547 us; speedup vs baseline: 1.1391x; 1.1391x over previous
//
#include <hip/hip_runtime.h>
#include <stdint.h>

#define H_ 4
#define N_ 512
#define D_ 64
#define E_ (N_ * N_)        // 262144 edges per head
#define HE_ (H_ * E_)       // 1048576
#define EPS_ 1e-10f

// Partitionable threefry (verified rounds 1-3): counter (hi=0, lo=j), out = x0^x1.
__device__ __forceinline__ void tf2x32(unsigned x0, unsigned x1,
                                       unsigned& o0, unsigned& o1) {
  const unsigned ks0 = 0u;          // key hi of seed 42
  const unsigned ks1 = 42u;         // key lo
  const unsigned ks2 = 0x1BD11BDAu ^ ks0 ^ ks1;
  x0 += ks0; x1 += ks1;
#define TFR(r) { x0 += x1; x1 = (x1 << (r)) | (x1 >> (32 - (r))); x1 ^= x0; }
  TFR(13) TFR(15) TFR(26) TFR(6)
  x0 += ks1; x1 += ks2 + 1u;
  TFR(17) TFR(29) TFR(16) TFR(24)
  x0 += ks2; x1 += ks0 + 2u;
  TFR(13) TFR(15) TFR(26) TFR(6)
  x0 += ks0; x1 += ks1 + 3u;
  TFR(17) TFR(29) TFR(16) TFR(24)
  x0 += ks1; x1 += ks2 + 4u;
  TFR(13) TFR(15) TFR(26) TFR(6)
  x0 += ks2; x1 += ks0 + 5u;
#undef TFR
  o0 = x0; o1 = x1;
}

__device__ __forceinline__ unsigned rng_bits(unsigned j) {
  unsigned a, b;
  tf2x32(0u, j, a, b);
  return a ^ b;
}

__device__ __forceinline__ float u01(unsigned bits) {
  return __uint_as_float((bits >> 9) | 0x3f800000u) - 1.0f;
}

// ---------------- node projection + zero of the done counters
__global__ __launch_bounds__(256) void precompute_ab(
    const float* __restrict__ feats, const float* __restrict__ W_out,
    float* __restrict__ A, float* __restrict__ B,
    unsigned* __restrict__ done) {
  int row = blockIdx.x * 4 + (threadIdx.x >> 6);   // h*N + n
  int d = threadIdx.x & 63;
  if (blockIdx.x == 0 && threadIdx.x < 4) done[threadIdx.x] = 0u;  // ws poisoned
  __shared__ float f[4][64];
  f[threadIdx.x >> 6][d] = feats[row * D_ + d];
  __syncthreads();
  const float* fr = f[threadIdx.x >> 6];
  float a = 0.f, b = 0.f;
#pragma unroll 8
  for (int k = 0; k < D_; ++k) {
    float fv = fr[k];
    a = fmaf(fv, W_out[k * D_ + d], a);          // sender rows [0,64)
    b = fmaf(fv, W_out[(k + D_) * D_ + d], b);   // receiver rows [64,128)
  }
  A[row * D_ + d] = a;
  B[row * D_ + d] = b;
}

// ---------------- fused edge + top-k kernel.
// 32 snd x 16 rec tile, 2 edges/thread, 2048 blocks = 8 blocks/CU
// (32 waves/CU, 2x the old 1024-block grid) to hide the serial
// threefry/logf chains. LDS ~13.6 KB; VGPR expected ~44 (<=64 keeps
// 8 waves/SIMD). Round-8 lesson: NO grid-wide barrier (50 us/ea on
// 8 XCDs); the only cross-block sync is the done-counter
// release/acquire pattern verified 4x in the old topk_fused.
__global__ __launch_bounds__(256, 4) void edge_topk(
    const float* __restrict__ A, const float* __restrict__ B,
    const float* __restrict__ b_out, const float* __restrict__ W_cat,
    const float* __restrict__ b_cat, float* __restrict__ out,
    unsigned long long* __restrict__ blockmax, unsigned* __restrict__ done) {
  __shared__ __align__(16) float Ash[32][68];   // stride 68: rows 16B-aligned,
                                                // stride%32==4: full bank spread
  __shared__ __align__(16) float Bsh[16][64];
  __shared__ float4 bsh4[16];
  __shared__ float4 wc4[32];
  __shared__ float bc2[2];
  __shared__ unsigned long long wmax[4];
  __shared__ unsigned long long thrS;
  __shared__ unsigned tkS, cntS;

  const int t = threadIdx.x;
  const int h = blockIdx.z;
  const int snd_base = blockIdx.x * 32;
  const int rec_base = blockIdx.y * 16;
  const int chunk = blockIdx.y * 16 + blockIdx.x;   // 0..511 within head

  {
    const float4* A4 = (const float4*)(A + (h * N_ + snd_base) * D_);
    for (int i = t; i < 512; i += 256)           // 32 rows x 16 float4
      *(float4*)&Ash[i >> 4][(i & 15) << 2] = A4[i];
    const float4* B4 = (const float4*)(B + (h * N_ + rec_base) * D_);
    *(float4*)&Bsh[t >> 4][(t & 15) << 2] = B4[t];   // 16 rows x 16 float4
  }
  if (t < 16) bsh4[t] = ((const float4*)b_out)[t];
  else if (t < 48) wc4[t - 16] = ((const float4*)W_cat)[t - 16];
  else if (t == 48) { bc2[0] = b_cat[0]; bc2[1] = b_cat[1]; }
  __syncthreads();

  const int s = t & 31;            // sender lane
  const int rg = (t >> 5) * 2;     // receiver group (2 rec/thread)

  float l0[2], l1[2];
#pragma unroll
  for (int r = 0; r < 2; ++r) { l0[r] = 0.f; l1[r] = 0.f; }

  // Per edge the fp chain is EXACTLY: for d=0..63 { t=relu((A+B)+b); l=fma(t,w,l) }
#pragma unroll
  for (int d4 = 0; d4 < 16; ++d4) {
    const float4 a0 = *(const float4*)&Ash[s][d4 << 2];
    const float4 bd = bsh4[d4];
    const float4 wA = wc4[2 * d4];
    const float4 wB = wc4[2 * d4 + 1];
#pragma unroll
    for (int r = 0; r < 2; ++r) {
      const float4 bv = *(const float4*)&Bsh[rg + r][d4 << 2];
      float t0;
      t0 = fmaxf((a0.x + bv.x) + bd.x, 0.f);
      l0[r] = fmaf(t0, wA.x, l0[r]); l1[r] = fmaf(t0, wA.y, l1[r]);
      t0 = fmaxf((a0.y + bv.y) + bd.y, 0.f);
      l0[r] = fmaf(t0, wA.z, l0[r]); l1[r] = fmaf(t0, wA.w, l1[r]);
      t0 = fmaxf((a0.z + bv.z) + bd.z, 0.f);
      l0[r] = fmaf(t0, wB.x, l0[r]); l1[r] = fmaf(t0, wB.y, l1[r]);
      t0 = fmaxf((a0.w + bv.w) + bd.w, 0.f);
      l0[r] = fmaf(t0, wB.z, l0[r]); l1[r] = fmaf(t0, wB.w, l1[r]);
    }
  }

  unsigned long long mk = 0ull;
#pragma unroll
  for (int r = 0; r < 2; ++r) {
    float L0 = l0[r] + bc2[0];
    float L1 = l1[r] + bc2[1];
    const unsigned snd = (unsigned)(snd_base + s);
    const unsigned rec = (unsigned)(rec_base + rg + r);
    const unsigned e = rec * (unsigned)N_ + snd;
    const unsigned base = ((unsigned)h << 18) + e;
    const unsigned j0 = base * 2u;

    float uu0 = u01(rng_bits(j0));
    float uu1 = u01(rng_bits(j0 + 1u));
    float g0 = -logf(-logf(uu0 + EPS_) + EPS_);
    float g1 = -logf(-logf(uu1 + EPS_) + EPS_);

    // argmax(softmax((l+g)/0.5)) == (L1+g1 > L0+g0): /0.5 exact, softmax monotone
    float cm = ((L1 + g1) > (L0 + g0)) ? 1.0f : 0.0f;

    float lm = fmaxf(L0, L1);
    float p0 = expf(L0 - lm), p1 = expf(L1 - lm);
    float pr = p1 / (p0 + p1);

    out[base] = cm;
    out[HE_ + base] = pr;

    unsigned long long key =
        ((unsigned long long)__float_as_uint(pr) << 32) | (unsigned)(~e);
    mk = key > mk ? key : mk;
  }

  // zero this block's flat 512-edge sparse chunk (winners scattered by tail)
  {
    float4* sp = (float4*)(out + 2 * HE_ + ((unsigned)h << 18) +
                           (unsigned)chunk * 512u);
    if (t < 128) sp[t] = make_float4(0.f, 0.f, 0.f, 0.f);
  }

#pragma unroll
  for (int off = 32; off; off >>= 1) {
    unsigned long long o = __shfl_xor(mk, off, 64);
    mk = o > mk ? o : mk;
  }
  if ((t & 63) == 0) wmax[t >> 6] = mk;
  __syncthreads();
  if (t == 0) {
    unsigned long long m = wmax[0];
#pragma unroll
    for (int i = 1; i < 4; ++i) m = wmax[i] > m ? wmax[i] : m;
    blockmax[h * 512 + chunk] = m;               // 512 chunks/head
  }

  // -------- done-counter (verified release/acquire): last block finishes --
  __syncthreads();
  if (t == 0) { __threadfence(); tkS = atomicAdd(&done[h], 1u); }  // release
  __syncthreads();
  if (tkS != 511u) return;

  // ======== tail: one block per head does threshold + compact + select ====
  if (t == 0) __threadfence();                   // acquire
  __syncthreads();

  unsigned long long* keyS = (unsigned long long*)&Ash[0][0];   // 4096 B
  unsigned long long* candS = keyS + 512;                       // 4096 B (8192<=8704)
  keyS[t] = blockmax[h * 512 + t];
  keyS[t + 256] = blockmax[h * 512 + 256 + t];
  if (t == 0) cntS = 0u;
  __syncthreads();
  {
    // threshold = 64th-largest of 512 chunk maxes (exact; keys unique).
    // >=64 elements have key >= thr (one per top-64 chunk), so the true
    // 64th-largest element key >= thr: all top-64 elements survive.
    unsigned long long k0 = keyS[t], k1 = keyS[t + 256];
    int r0 = 0, r1 = 0;
    for (int j = 0; j < 512; ++j) {
      unsigned long long kj = keyS[j];
      r0 += (kj > k0);
      r1 += (kj > k1);
    }
    if (r0 == 63) thrS = k0;
    if (r1 == 63) thrS = k1;
  }
  __syncthreads();
  const unsigned long long thr = thrS;

  // scan this head's 262144 probs (1 MB, L2-warm), compact keys >= thr
  {
    const float4* P4 = (const float4*)(out + HE_ + ((unsigned)h << 18));
    for (int i = 0; i < 256; ++i) {
      const unsigned idx = (unsigned)i * 256u + (unsigned)t;
      float4 p = P4[idx];
      const unsigned e0 = idx * 4u;
      float pv[4] = {p.x, p.y, p.z, p.w};
#pragma unroll
      for (int k2 = 0; k2 < 4; ++k2) {
        unsigned long long key =
            ((unsigned long long)__float_as_uint(pv[k2]) << 32) |
            (unsigned)(~(e0 + (unsigned)k2));
        if (key >= thr) {
          unsigned pos = atomicAdd(&cntS, 1u);   // ~70-160 expected << 512
          if (pos < 512u) candS[pos] = key;
        }
      }
    }
  }
  __syncthreads();
  unsigned n = cntS;
  if (n > 512u) n = 512u;
  if (t >= (int)n) candS[t] = 0ull;              // zero-pad unfilled slots
  if (t + 256 >= (int)n) candS[t + 256] = 0ull;
  __syncthreads();
  {
    unsigned long long m0 = candS[t], m1 = candS[t + 256];
    int r0 = 0, r1 = 0;
#pragma unroll 8
    for (int j = 0; j < 512; ++j) {
      unsigned long long kj = candS[j];
      r0 += (kj > m0);
      r1 += (kj > m1);
    }
    if (m0 != 0ull && r0 < 64) {
      unsigned e = ~(unsigned)(m0 & 0xFFFFFFFFull);
      if (e < (unsigned)E_) out[2 * HE_ + ((unsigned)h << 18) + e] = 1.0f;
    }
    if (m1 != 0ull && r1 < 64) {
      unsigned e = ~(unsigned)(m1 & 0xFFFFFFFFull);
      if (e < (unsigned)E_) out[2 * HE_ + ((unsigned)h << 18) + e] = 1.0f;
    }
  }
}

extern "C" void kernel_launch(void* const* d_in, const int* in_sizes, int n_in,
                              void* d_out, int out_size, void* d_ws, size_t ws_size,
                              hipStream_t stream) {
  const float* feats = (const float*)d_in[0];
  const float* W_out = (const float*)d_in[1];
  const float* b_out = (const float*)d_in[2];
  const float* W_cat = (const float*)d_in[3];
  const float* b_cat = (const float*)d_in[4];
  float* out = (float*)d_out;

  // workspace: A | B | blockmax(H*512) | done(4)
  float* A = (float*)d_ws;
  float* B = A + H_ * N_ * D_;
  unsigned long long* blockmax = (unsigned long long*)(B + H_ * N_ * D_);
  unsigned* done = (unsigned*)(blockmax + H_ * 512);

  precompute_ab<<<dim3(H_ * N_ / 4), dim3(256), 0, stream>>>(feats, W_out, A, B,
                                                             done);
  edge_topk<<<dim3(N_ / 32, N_ / 16, H_), dim3(256), 0, stream>>>(
      A, B, b_out, W_cat, b_cat, out, blockmax, done);
}

// Round 10
// 210.670 us; speedup vs baseline: 1.3656x; 1.1988x over previous
//
#include <hip/hip_runtime.h>
#include <stdint.h>

#define H_ 4
#define N_ 512
#define D_ 64
#define E_ (N_ * N_)        // 262144 edges per head
#define HE_ (H_ * E_)       // 1048576
#define EPS_ 1e-10f

// Partitionable threefry (verified rounds 1-3): counter (hi=0, lo=j), out = x0^x1.
__device__ __forceinline__ void tf2x32(unsigned x0, unsigned x1,
                                       unsigned& o0, unsigned& o1) {
  const unsigned ks0 = 0u;          // key hi of seed 42
  const unsigned ks1 = 42u;         // key lo
  const unsigned ks2 = 0x1BD11BDAu ^ ks0 ^ ks1;
  x0 += ks0; x1 += ks1;
#define TFR(r) { x0 += x1; x1 = (x1 << (r)) | (x1 >> (32 - (r))); x1 ^= x0; }
  TFR(13) TFR(15) TFR(26) TFR(6)
  x0 += ks1; x1 += ks2 + 1u;
  TFR(17) TFR(29) TFR(16) TFR(24)
  x0 += ks2; x1 += ks0 + 2u;
  TFR(13) TFR(15) TFR(26) TFR(6)
  x0 += ks0; x1 += ks1 + 3u;
  TFR(17) TFR(29) TFR(16) TFR(24)
  x0 += ks1; x1 += ks2 + 4u;
  TFR(13) TFR(15) TFR(26) TFR(6)
  x0 += ks2; x1 += ks0 + 5u;
#undef TFR
  o0 = x0; o1 = x1;
}

__device__ __forceinline__ unsigned rng_bits(unsigned j) {
  unsigned a, b;
  tf2x32(0u, j, a, b);
  return a ^ b;
}

__device__ __forceinline__ float u01(unsigned bits) {
  return __uint_as_float((bits >> 9) | 0x3f800000u) - 1.0f;
}

// ---------------- single fused kernel: A/B projection (block-local,
// redundant but cheap: ~5 us chip-wide VALU) + edge math + fused top-k.
// 32 snd x 16 rec tile, 2 edges/thread, 2048 blocks. LDS ~17.7 KB.
// Round-9 lesson: the per-head tail scan MUST batch loads (8 outstanding)
// or it serializes on ~700-cyc L2/L3 misses (was 165 us). Round-8 lesson:
// no grid-wide barrier; only the verified done-counter release/acquire.
// Round-3 lesson: all arrays statically indexed (full unroll), no VGPR caps.
__global__ __launch_bounds__(256, 4) void edge_topk(
    const float* __restrict__ feats, const float* __restrict__ W_out,
    const float* __restrict__ b_out, const float* __restrict__ W_cat,
    const float* __restrict__ b_cat, float* __restrict__ out,
    unsigned long long* __restrict__ blockmax, unsigned* __restrict__ done) {
  __shared__ __align__(16) float Ash[32][68];   // stride 68: rows 16B-aligned,
                                                // stride%32==4: full bank spread
  __shared__ __align__(16) float Bsh[16][64];
  __shared__ __align__(16) float FX[16][64];    // feats staging scratch (4 KB)
  __shared__ float4 bsh4[16];
  __shared__ float4 wc4[32];
  __shared__ float bc2[2];
  __shared__ unsigned long long wmax[4];
  __shared__ unsigned long long thrS;
  __shared__ unsigned tkS, cntS;

  const int t = threadIdx.x;
  const int h = blockIdx.z;
  const int snd_base = blockIdx.x * 32;
  const int rec_base = blockIdx.y * 16;
  const int chunk = blockIdx.y * 16 + blockIdx.x;   // 0..511 within head

  if (t < 16) bsh4[t] = ((const float4*)b_out)[t];
  else if (t < 48) wc4[t - 16] = ((const float4*)W_cat)[t - 16];
  else if (t == 48) { bc2[0] = b_cat[0]; bc2[1] = b_cat[1]; }

  // ======== phase A: block-local A/B projection ========
  // Per-element FP chain IDENTICAL to the old precompute_ab:
  // acc = fmaf(feats[row][k], W_out[k*64+d], acc), k ascending.
  const int d = t & 63;
  const int g4 = (t >> 6) * 4;                  // 4 rows per thread-group
  const float4* F4 = (const float4*)feats;

#pragma unroll
  for (int half = 0; half < 2; ++half) {        // A rows: 2 halves of 16
    *(float4*)&FX[t >> 4][(t & 15) << 2] =
        F4[(h * N_ + snd_base + half * 16 + (t >> 4)) * 16 + (t & 15)];
    __syncthreads();
    float a0 = 0.f, a1 = 0.f, a2 = 0.f, a3 = 0.f;
#pragma unroll 8
    for (int k = 0; k < D_; ++k) {
      const float w = W_out[k * D_ + d];        // coalesced 256B/k, L2-hot
      a0 = fmaf(FX[g4 + 0][k], w, a0);
      a1 = fmaf(FX[g4 + 1][k], w, a1);
      a2 = fmaf(FX[g4 + 2][k], w, a2);
      a3 = fmaf(FX[g4 + 3][k], w, a3);
    }
    Ash[half * 16 + g4 + 0][d] = a0;
    Ash[half * 16 + g4 + 1][d] = a1;
    Ash[half * 16 + g4 + 2][d] = a2;
    Ash[half * 16 + g4 + 3][d] = a3;
    __syncthreads();                            // FX consumed; safe to restage
  }
  {                                             // B rows: 16 rec rows
    *(float4*)&FX[t >> 4][(t & 15) << 2] =
        F4[(h * N_ + rec_base + (t >> 4)) * 16 + (t & 15)];
    __syncthreads();
    float b0 = 0.f, b1 = 0.f, b2 = 0.f, b3 = 0.f;
#pragma unroll 8
    for (int k = 0; k < D_; ++k) {
      const float w = W_out[(k + D_) * D_ + d]; // receiver rows [64,128)
      b0 = fmaf(FX[g4 + 0][k], w, b0);
      b1 = fmaf(FX[g4 + 1][k], w, b1);
      b2 = fmaf(FX[g4 + 2][k], w, b2);
      b3 = fmaf(FX[g4 + 3][k], w, b3);
    }
    Bsh[g4 + 0][d] = b0;
    Bsh[g4 + 1][d] = b1;
    Bsh[g4 + 2][d] = b2;
    Bsh[g4 + 3][d] = b3;
    __syncthreads();                            // Ash/Bsh ready for edge loop
  }

  // ======== phase B: edge math (verbatim round-9 FP chains) ========
  const int s = t & 31;            // sender lane
  const int rg = (t >> 5) * 2;     // receiver group (2 rec/thread)

  float l0[2], l1[2];
#pragma unroll
  for (int r = 0; r < 2; ++r) { l0[r] = 0.f; l1[r] = 0.f; }

  // Per edge the fp chain is EXACTLY: for d=0..63 { t=relu((A+B)+b); l=fma(t,w,l) }
#pragma unroll
  for (int d4 = 0; d4 < 16; ++d4) {
    const float4 a0 = *(const float4*)&Ash[s][d4 << 2];
    const float4 bd = bsh4[d4];
    const float4 wA = wc4[2 * d4];
    const float4 wB = wc4[2 * d4 + 1];
#pragma unroll
    for (int r = 0; r < 2; ++r) {
      const float4 bv = *(const float4*)&Bsh[rg + r][d4 << 2];
      float t0;
      t0 = fmaxf((a0.x + bv.x) + bd.x, 0.f);
      l0[r] = fmaf(t0, wA.x, l0[r]); l1[r] = fmaf(t0, wA.y, l1[r]);
      t0 = fmaxf((a0.y + bv.y) + bd.y, 0.f);
      l0[r] = fmaf(t0, wA.z, l0[r]); l1[r] = fmaf(t0, wA.w, l1[r]);
      t0 = fmaxf((a0.z + bv.z) + bd.z, 0.f);
      l0[r] = fmaf(t0, wB.x, l0[r]); l1[r] = fmaf(t0, wB.y, l1[r]);
      t0 = fmaxf((a0.w + bv.w) + bd.w, 0.f);
      l0[r] = fmaf(t0, wB.z, l0[r]); l1[r] = fmaf(t0, wB.w, l1[r]);
    }
  }

  unsigned long long mk = 0ull;
#pragma unroll
  for (int r = 0; r < 2; ++r) {
    float L0 = l0[r] + bc2[0];
    float L1 = l1[r] + bc2[1];
    const unsigned snd = (unsigned)(snd_base + s);
    const unsigned rec = (unsigned)(rec_base + rg + r);
    const unsigned e = rec * (unsigned)N_ + snd;
    const unsigned base = ((unsigned)h << 18) + e;
    const unsigned j0 = base * 2u;

    float uu0 = u01(rng_bits(j0));
    float uu1 = u01(rng_bits(j0 + 1u));
    float g0 = -logf(-logf(uu0 + EPS_) + EPS_);
    float g1 = -logf(-logf(uu1 + EPS_) + EPS_);

    // argmax(softmax((l+g)/0.5)) == (L1+g1 > L0+g0): /0.5 exact, softmax monotone
    float cm = ((L1 + g1) > (L0 + g0)) ? 1.0f : 0.0f;

    float lm = fmaxf(L0, L1);
    float p0 = expf(L0 - lm), p1 = expf(L1 - lm);
    float pr = p1 / (p0 + p1);

    out[base] = cm;
    out[HE_ + base] = pr;

    unsigned long long key =
        ((unsigned long long)__float_as_uint(pr) << 32) | (unsigned)(~e);
    mk = key > mk ? key : mk;
  }

  // zero this block's flat 512-edge sparse chunk (winners scattered by tail)
  {
    float4* sp = (float4*)(out + 2 * HE_ + ((unsigned)h << 18) +
                           (unsigned)chunk * 512u);
    if (t < 128) sp[t] = make_float4(0.f, 0.f, 0.f, 0.f);
  }

#pragma unroll
  for (int off = 32; off; off >>= 1) {
    unsigned long long o = __shfl_xor(mk, off, 64);
    mk = o > mk ? o : mk;
  }
  if ((t & 63) == 0) wmax[t >> 6] = mk;
  __syncthreads();
  if (t == 0) {
    unsigned long long m = wmax[0];
#pragma unroll
    for (int i = 1; i < 4; ++i) m = wmax[i] > m ? wmax[i] : m;
    blockmax[h * 512 + chunk] = m;               // 512 chunks/head
  }

  // -------- done-counter (verified release/acquire): last block finishes --
  __syncthreads();
  if (t == 0) { __threadfence(); tkS = atomicAdd(&done[h], 1u); }  // release
  __syncthreads();
  if (tkS != 511u) return;

  // ======== tail: one block per head: threshold + compact + select ====
  if (t == 0) __threadfence();                   // acquire
  __syncthreads();

  unsigned long long* keyS = (unsigned long long*)&Ash[0][0];   // 4096 B
  unsigned long long* candS = keyS + 512;                       // 4096 B (8192<=8704)
  keyS[t] = blockmax[h * 512 + t];
  keyS[t + 256] = blockmax[h * 512 + 256 + t];
  if (t == 0) cntS = 0u;
  __syncthreads();
  {
    // threshold = 64th-largest of 512 chunk maxes (exact; keys unique).
    // >=64 elements have key >= thr, so the true 64th-largest element key
    // >= thr: all top-64 elements survive the filter.
    unsigned long long k0 = keyS[t], k1 = keyS[t + 256];
    int r0 = 0, r1 = 0;
    for (int j = 0; j < 512; ++j) {
      unsigned long long kj = keyS[j];
      r0 += (kj > k0);
      r1 += (kj > k1);
    }
    if (r0 == 63) thrS = k0;
    if (r1 == 63) thrS = k1;
  }
  __syncthreads();
  const unsigned long long thr = thrS;

  // scan this head's 262144 probs: 8-deep load batching (statically indexed
  // regs) keeps 8 misses in flight -> ~12 us instead of round-9's 165 us.
  {
    const float4* P4 = (const float4*)(out + HE_ + ((unsigned)h << 18));
    for (int g2 = 0; g2 < 32; ++g2) {
      float4 buf[8];
#pragma unroll
      for (int k = 0; k < 8; ++k)
        buf[k] = P4[(unsigned)(g2 * 8 + k) * 256u + (unsigned)t];
#pragma unroll
      for (int k = 0; k < 8; ++k) {
        const unsigned idx = (unsigned)(g2 * 8 + k) * 256u + (unsigned)t;
        const unsigned e0 = idx * 4u;
        float pv[4] = {buf[k].x, buf[k].y, buf[k].z, buf[k].w};
#pragma unroll
        for (int k2 = 0; k2 < 4; ++k2) {
          unsigned long long key =
              ((unsigned long long)__float_as_uint(pv[k2]) << 32) |
              (unsigned)(~(e0 + (unsigned)k2));
          if (key >= thr) {
            unsigned pos = atomicAdd(&cntS, 1u);   // ~70-160 expected << 512
            if (pos < 512u) candS[pos] = key;
          }
        }
      }
    }
  }
  __syncthreads();
  unsigned n = cntS;
  if (n > 512u) n = 512u;
  if (t >= (int)n) candS[t] = 0ull;              // zero-pad unfilled slots
  if (t + 256 >= (int)n) candS[t + 256] = 0ull;
  __syncthreads();
  {
    unsigned long long m0 = candS[t], m1 = candS[t + 256];
    int r0 = 0, r1 = 0;
#pragma unroll 8
    for (int j = 0; j < 512; ++j) {
      unsigned long long kj = candS[j];
      r0 += (kj > m0);
      r1 += (kj > m1);
    }
    if (m0 != 0ull && r0 < 64) {
      unsigned e = ~(unsigned)(m0 & 0xFFFFFFFFull);
      if (e < (unsigned)E_) out[2 * HE_ + ((unsigned)h << 18) + e] = 1.0f;
    }
    if (m1 != 0ull && r1 < 64) {
      unsigned e = ~(unsigned)(m1 & 0xFFFFFFFFull);
      if (e < (unsigned)E_) out[2 * HE_ + ((unsigned)h << 18) + e] = 1.0f;
    }
  }
}

extern "C" void kernel_launch(void* const* d_in, const int* in_sizes, int n_in,
                              void* d_out, int out_size, void* d_ws, size_t ws_size,
                              hipStream_t stream) {
  const float* feats = (const float*)d_in[0];
  const float* W_out = (const float*)d_in[1];
  const float* b_out = (const float*)d_in[2];
  const float* W_cat = (const float*)d_in[3];
  const float* b_cat = (const float*)d_in[4];
  float* out = (float*)d_out;

  // workspace: blockmax(H*512) | done(4)
  unsigned long long* blockmax = (unsigned long long*)d_ws;
  unsigned* done = (unsigned*)(blockmax + H_ * 512);

  // zero the 4 done counters (ws poisoned 0xAA each call); stream-ordered,
  // graph-capture legal (verified round 8).
  hipMemsetAsync((void*)done, 0, 4 * sizeof(unsigned), stream);

  edge_topk<<<dim3(N_ / 32, N_ / 16, H_), dim3(256), 0, stream>>>(
      feats, W_out, b_out, W_cat, b_cat, out, blockmax, done);
}